// Round 10
// baseline (306.341 us; speedup 1.0000x reference)
//
#include <hip/hip_runtime.h>

#define N 8192
#define D 512
#define KNEI 10
#define NC 6
#define NUNIT 64
#define TRS 20
#define NTOT (NUNIT * NC)  // 384 candidates per row

typedef __attribute__((ext_vector_type(8))) short bfv8;
typedef __attribute__((ext_vector_type(8))) unsigned short usv8;
typedef __attribute__((ext_vector_type(4))) float fv4;
typedef unsigned int uint32;

#define GLOAD_LDS16(gp, lp)                                                  \
  __builtin_amdgcn_global_load_lds(                                          \
      (const __attribute__((address_space(1))) void*)(gp),                   \
      (__attribute__((address_space(3))) void*)(lp), 16, 0, 0)

__device__ inline unsigned short f2bf(float f) {
  unsigned int u = __float_as_uint(f);
  return (unsigned short)((u + 0x7fffu + ((u >> 16) & 1u)) >> 16);
}

// ---------------------------------------------------------------------------
// Kernel 0: per-row fp32 sq (numpy-pairwise-style; validated rounds 3-8).
// ---------------------------------------------------------------------------
__global__ __launch_bounds__(256) void row_sq_np_kernel(const float* __restrict__ x,
                                                        float* __restrict__ sq) {
  const int wave = threadIdx.x >> 6;
  const int lane = threadIdx.x & 63;
  const int row = blockIdx.x * 4 + wave;
  const float* xr = x + (size_t)row * D;

  float s = 0.f;
  if (lane < 32) {
    const int leaf = lane >> 3;
    const int j = lane & 7;
    const float* a = xr + leaf * 128;
    float v = a[j];
    s = __fmul_rn(v, v);
#pragma unroll
    for (int i = 8; i < 128; i += 8) {
      v = a[i + j];
      s = __fadd_rn(s, __fmul_rn(v, v));
    }
  }
  float t1 = __shfl_xor(s, 1);
  s = __fadd_rn(s, t1);
  float t2 = __shfl_xor(s, 2);
  s = __fadd_rn(s, t2);
  float t4 = __shfl_xor(s, 4);
  s = __fadd_rn(s, t4);
  const float L0 = __shfl(s, 0);
  const float L1 = __shfl(s, 8);
  const float L2 = __shfl(s, 16);
  const float L3 = __shfl(s, 24);
  const float total = __fadd_rn(__fadd_rn(L0, L1), __fadd_rn(L2, L3));
  if (lane == 0) sq[row] = total;
}

// ---------------------------------------------------------------------------
// Kernel 0b: fp32 -> bf16 (RTNE) — reverted from fp8 (recall failure r9).
// ---------------------------------------------------------------------------
__global__ __launch_bounds__(256) void cvt_bf16_kernel(const float* __restrict__ x,
                                                       unsigned short* __restrict__ xb) {
  const int base = (blockIdx.x * 256 + threadIdx.x) * 8;
  const float4 a = *(const float4*)(x + base);
  const float4 b = *(const float4*)(x + base + 4);
  usv8 o;
  o[0] = f2bf(a.x); o[1] = f2bf(a.y); o[2] = f2bf(a.z); o[3] = f2bf(a.w);
  o[4] = f2bf(b.x); o[5] = f2bf(b.y); o[6] = f2bf(b.z); o[7] = f2bf(b.w);
  *(usv8*)(xb + base) = o;
}

// ---------------------------------------------------------------------------
// Kernel 1: SYMMETRIC-TRIANGLE bf16 MFMA Gram + dual-side selection.
// Grid = 2080 upper-triangle (bi<=bj) 128x128 tile pairs — 50.8% of the
// full Gram's MFMA/staging work. 4 waves in 2x2, 64x64 tile each.
// Staging: K-chunk-major [c][row][16B] via global_load_lds w16 (conflict-free
// b128 frag reads, wave-uniform DMA dest). Scores: Ts[64][137] per col-half
// phase (137 = 9 mod 32 -> row-scan AND col-scan both 2 lanes/bank = free),
// staging aliased inside Ts. Selection: threads 0..127 = i-rows (unit bj),
// threads 128..191 = j-rows of the phase half (unit bi; skipped on diagonal).
// ---------------------------------------------------------------------------
__global__ __launch_bounds__(256, 3) void knn_gemm_tri(
    const unsigned short* __restrict__ xb, const float* __restrict__ sq,
    uint32* __restrict__ ck) {
  __shared__ __align__(16) float Ts[64 * 137];  // 35072 B; staging aliased
  __shared__ float sqi_s[128];
  __shared__ float sqj_s[128];
  char* As = (char*)Ts;          // [8][128][16B] = 16384 B
  char* Bs = (char*)Ts + 16384;  // [8][128][16B] = 16384 B

  const int tid = threadIdx.x;
  const int lane = tid & 63;
  const int wave = tid >> 6;
  const int wy = wave >> 1;
  const int wx = wave & 1;
  const int m = lane & 15;
  const int kg = lane >> 4;

  // Decode upper-triangle pair (bi <= bj).
  int bi = 0, rem = blockIdx.x;
  while (rem >= 64 - bi) {
    rem -= 64 - bi;
    ++bi;
  }
  const int bj = bi + rem;
  const int ibase = bi * 128;
  const int jbase = bj * 128;

  if (tid < 128) sqi_s[tid] = sq[ibase + tid];
  else sqj_s[tid - 128] = sq[jbase + tid - 128];

  fv4 acc[4][4];
#pragma unroll
  for (int fi = 0; fi < 4; ++fi)
#pragma unroll
    for (int fj = 0; fj < 4; ++fj) acc[fi][fj] = (fv4)(0.f);

  for (int kt = 0; kt < 8; ++kt) {
    __syncthreads();  // prior frag reads done; staging reusable
    // Wave w stages K-chunks c = 2w, 2w+1 for both stripes.
#pragma unroll
    for (int q = 0; q < 2; ++q) {
      const int c = wave * 2 + q;
      const int gk = kt * 64 + c * 8;  // element offset (8 bf16 = 16 B)
      GLOAD_LDS16(xb + (size_t)(ibase + lane) * D + gk, As + c * 2048);
      GLOAD_LDS16(xb + (size_t)(ibase + 64 + lane) * D + gk,
                  As + c * 2048 + 1024);
      GLOAD_LDS16(xb + (size_t)(jbase + lane) * D + gk, Bs + c * 2048);
      GLOAD_LDS16(xb + (size_t)(jbase + 64 + lane) * D + gk,
                  Bs + c * 2048 + 1024);
    }
    __syncthreads();  // staging visible (vmcnt drained at barrier)

#pragma unroll
    for (int kh = 0; kh < 2; ++kh) {
      const int c = kh * 4 + kg;
      bfv8 af[4], bf[4];
#pragma unroll
      for (int f = 0; f < 4; ++f) {
        af[f] = *(const bfv8*)(As + c * 2048 + (wy * 64 + f * 16 + m) * 16);
        bf[f] = *(const bfv8*)(Bs + c * 2048 + (wx * 64 + f * 16 + m) * 16);
      }
#pragma unroll
      for (int fi = 0; fi < 4; ++fi)
#pragma unroll
        for (int fj = 0; fj < 4; ++fj)
          acc[fi][fj] = __builtin_amdgcn_mfma_f32_16x16x32_bf16(
              af[fi], bf[fj], acc[fi][fj], 0, 0, 0);
    }
  }

  uint32 bkr[NC];  // row-side keys (threads < 128), unit bj
#pragma unroll
  for (int t = 0; t < NC; ++t) bkr[t] = 0xffffffffu;

#pragma unroll 1
  for (int ph = 0; ph < 2; ++ph) {
    __syncthreads();  // frag reads (ph0) / prior-phase Ts reads (ph1) done
    // Dump cols 64*ph..+63: Ts[col-in-half][row], C/D row = kg*4+reg.
    if (wx == ph) {
#pragma unroll
      for (int fi = 0; fi < 4; ++fi)
#pragma unroll
        for (int fj = 0; fj < 4; ++fj)
          *(fv4*)(&Ts[(fj * 16 + m) * 137 + wy * 64 + fi * 16 + kg * 4]) =
              acc[fi][fj];
    }
    __syncthreads();

    if (tid < 128) {
      // Row-side: i-row = tid over 64 cols of this half.
      const float sqo = sqi_s[tid];
#pragma unroll 1
      for (int c = 0; c < 64; ++c) {
        const float d = fmaxf(sqo - 2.f * Ts[c * 137 + tid] + sqj_s[ph * 64 + c], 0.f);
        const uint32 key =
            ((uint32)f2bf(d) << 16) | (uint32)(jbase + ph * 64 + c);
        if (key < bkr[NC - 1]) {
          uint32 kv = key;
#pragma unroll
          for (int t = 0; t < NC; ++t) {
            if (kv < bkr[t]) {
              const uint32 tmp = bkr[t];
              bkr[t] = kv;
              kv = tmp;
            }
          }
        }
      }
    } else if (tid < 192 && bi != bj) {
      // Col-side: j-row = 64*ph + (tid-128) over all 128 i-rows (unit bi).
      const int jl = tid - 128;
      const float sqo = sqj_s[ph * 64 + jl];
      uint32 bkc[NC];
#pragma unroll
      for (int t = 0; t < NC; ++t) bkc[t] = 0xffffffffu;
#pragma unroll 1
      for (int ii = 0; ii < 128; ++ii) {
        const float d = fmaxf(sqo - 2.f * Ts[jl * 137 + ii] + sqi_s[ii], 0.f);
        const uint32 key = ((uint32)f2bf(d) << 16) | (uint32)(ibase + ii);
        if (key < bkc[NC - 1]) {
          uint32 kv = key;
#pragma unroll
          for (int t = 0; t < NC; ++t) {
            if (kv < bkc[t]) {
              const uint32 tmp = bkc[t];
              bkc[t] = kv;
              kv = tmp;
            }
          }
        }
      }
      const size_t ob = ((size_t)(jbase + ph * 64 + jl) * NUNIT + bi) * NC;
#pragma unroll
      for (int t = 0; t < NC; ++t) ck[ob + t] = bkc[t];
    }
  }

  if (tid < 128) {
    const size_t ob = ((size_t)(ibase + tid) * NUNIT + bj) * NC;
#pragma unroll
    for (int t = 0; t < NC; ++t) ck[ob + t] = bkr[t];
  }
}

// ---------------------------------------------------------------------------
// Kernel 2: wave-per-row merge (validated round 8); only NTOT 256 -> 384
// (6 strided keys/lane in preselect). Comparator/rescore byte-identical.
// ---------------------------------------------------------------------------
__global__ __launch_bounds__(256) void merge_kernel(const float* __restrict__ x,
                                                    const float* __restrict__ sq,
                                                    const uint32* __restrict__ ck,
                                                    float* __restrict__ out) {
  __shared__ double zsh[4][TRS];
  __shared__ int jsh[4][TRS];
  __shared__ int jout[4][KNEI];

  const int wave = threadIdx.x >> 6;
  const int lane = threadIdx.x & 63;
  const int i = blockIdx.x * 4 + wave;

  const float4 xiA = *(const float4*)(x + (size_t)i * D + lane * 8);
  const float4 xiB = *(const float4*)(x + (size_t)i * D + lane * 8 + 4);
  const float sqi = sq[i];

  const uint32* ckr = ck + (size_t)i * NTOT;
  uint32 l[NC];
#pragma unroll
  for (int k = 0; k < NC; ++k) l[k] = ckr[lane + 64 * k];

  // (1) top-20 by packed key (bf16 score, then lower index — keys unique).
  int myselj = 0;
#pragma unroll 1
  for (int slot = 0; slot < TRS; ++slot) {
    uint32 r = l[0];
#pragma unroll
    for (int k = 1; k < NC; ++k) r = min(r, l[k]);
#pragma unroll
    for (int off = 32; off; off >>= 1) r = min(r, __shfl_xor(r, off));
    if (lane == slot) myselj = (int)(r & 0xffffu);
#pragma unroll
    for (int k = 0; k < NC; ++k)
      if (l[k] == r) l[k] = 0xffffffffu;
  }

  // (2) fp64 rescore with the reference's fp32 rounding chain (validated).
  double myz = 0.0;
#pragma unroll 2
  for (int c = 0; c < TRS; ++c) {
    const int j = __shfl(myselj, c);
    const float4 a = *(const float4*)(x + (size_t)j * D + lane * 8);
    const float4 b = *(const float4*)(x + (size_t)j * D + lane * 8 + 4);
    double s = (double)xiA.x * a.x + (double)xiA.y * a.y +
               (double)xiA.z * a.z + (double)xiA.w * a.w +
               (double)xiB.x * b.x + (double)xiB.y * b.y +
               (double)xiB.z * b.z + (double)xiB.w * b.w;
#pragma unroll
    for (int off = 32; off; off >>= 1) s += __shfl_xor(s, off);
    if (lane == c) {
      const float G = (float)s;
      const float y = __fsub_rn(sqi, __fmul_rn(2.0f, G));
      myz = (double)y + (double)sq[j];
    }
  }
  if (lane < TRS) {
    zsh[wave][lane] = myz;
    jsh[wave][lane] = myselj;
  }
  __syncthreads();

  // (3) serial top-10, eps tie-break — comparator identical to rounds 3-8.
  if (lane == 0) {
    unsigned int used = 0u;
    for (int slot = 0; slot < KNEI; ++slot) {
      int b = -1;
      double zb = 0.0;
      for (int c = 0; c < TRS; ++c) {
        if ((used >> c) & 1u) continue;
        const double zc = zsh[wave][c];
        if (b < 0) {
          b = c;
          zb = zc;
          continue;
        }
        const double eps = 1.25e-7 * fabs(zb);
        bool better;
        if (zc < zb - eps) better = true;
        else if (zc > zb + eps) better = false;
        else better = (jsh[wave][c] < jsh[wave][b]);
        if (better) {
          b = c;
          zb = zc;
        }
      }
      used |= (1u << b);
      jout[wave][slot] = jsh[wave][b];
    }
  }
  __syncthreads();

  // (4) smoothed = 0.5*x + 0.05 * sum(neighbors); 8 dims per lane.
  float4 sA = {0.f, 0.f, 0.f, 0.f}, sB = {0.f, 0.f, 0.f, 0.f};
#pragma unroll
  for (int mth = 0; mth < KNEI; ++mth) {
    const int j = jout[wave][mth];
    const float4 a = *(const float4*)(x + (size_t)j * D + lane * 8);
    const float4 b = *(const float4*)(x + (size_t)j * D + lane * 8 + 4);
    sA.x += a.x; sA.y += a.y; sA.z += a.z; sA.w += a.w;
    sB.x += b.x; sB.y += b.y; sB.z += b.z; sB.w += b.w;
  }
  float4 oA, oB;
  oA.x = 0.5f * xiA.x + 0.05f * sA.x;
  oA.y = 0.5f * xiA.y + 0.05f * sA.y;
  oA.z = 0.5f * xiA.z + 0.05f * sA.z;
  oA.w = 0.5f * xiA.w + 0.05f * sA.w;
  oB.x = 0.5f * xiB.x + 0.05f * sB.x;
  oB.y = 0.5f * xiB.y + 0.05f * sB.y;
  oB.z = 0.5f * xiB.z + 0.05f * sB.z;
  oB.w = 0.5f * xiB.w + 0.05f * sB.w;
  *(float4*)(out + (size_t)i * D + lane * 8) = oA;
  *(float4*)(out + (size_t)i * D + lane * 8 + 4) = oB;
}

// ---------------------------------------------------------------------------
extern "C" void kernel_launch(void* const* d_in, const int* in_sizes, int n_in,
                              void* d_out, int out_size, void* d_ws, size_t ws_size,
                              hipStream_t stream) {
  const float* x = (const float*)d_in[0];
  float* out = (float*)d_out;

  char* ws = (char*)d_ws;
  float* sq = (float*)ws;                              // 32 KB
  unsigned short* xb = (unsigned short*)(ws + 32768);  // 8 MB bf16
  uint32* ck = (uint32*)(ws + 32768 + 8388608);        // 12.6 MB keys

  row_sq_np_kernel<<<N / 4, 256, 0, stream>>>(x, sq);
  cvt_bf16_kernel<<<(N * D) / (8 * 256), 256, 0, stream>>>(x, xb);
  knn_gemm_tri<<<2080, 256, 0, stream>>>(xb, sq, ck);
  merge_kernel<<<N / 4, 256, 0, stream>>>(x, sq, ck, out);
}